// Round 7
// baseline (70.120 us; speedup 1.0000x reference)
//
#include <hip/hip_runtime.h>
#include <hip/hip_bf16.h>

// ST-GCN spatial graph conv — single-wave fused two-stage MFMA, ZERO LDS, ZERO barriers.
//
// Wave owns one (n,t). Stage1: F[kc][v] = X^T @ W^T (2 v-halves x 12 kc-tiles x 2 ks).
// Lane ends holding F[kc=16j+lr][v=16h+4q+r]. Stage2 B-frag (16x16x32) needs
// B[k=8q+e][c=16cn+lr] = F'[khat][c] — choosing khat(q,e) = 32g+16(e>>2)+4q+(e&3)
// makes B-frag == lane's own acc (bf16-converted), zero cross-lane movement.
// The Ahat ws image is PRE-PERMUTED to that (g,q,e) layout (zeros kill v>=25 pads).
// Bias folded into bout[c][w] out-init (computed in prepass).
//
// ws images: Wbf[192 kc][64 ci] bf16 | Ahat2[32 w][3 g][4 q][8 e] bf16 | bout[64 c][32 w] f32

#define CIN   64
#define T_    300
#define V_    25
#define OC    192
#define COUT  64

#define WS_W    0        // 24576 B
#define WS_A2   24576    // 6144 B
#define WS_B    30720    // 8192 B
#define WS_BYTES 38912

typedef short  bf16x8 __attribute__((ext_vector_type(8)));
typedef float  f32x4  __attribute__((ext_vector_type(4)));

__device__ __forceinline__ unsigned short cvt_bf16(float f) {
    union { __hip_bfloat16 h; unsigned short u; } cv;
    cv.h = __float2bfloat16(f);
    return cv.u;
}

// ---------------- prepass ----------------
__global__ void gcn_prep(const float* __restrict__ W, const float* __restrict__ bias,
                         const float* __restrict__ A, unsigned char* __restrict__ ws)
{
    const int tid = blockIdx.x * 256 + threadIdx.x;   // 4096 threads
    // W bf16 image, natural [kc][ci]
    for (int i = tid; i < OC * CIN; i += 4096)
        reinterpret_cast<unsigned short*>(ws + WS_W)[i] = cvt_bf16(W[i]);
    // Ahat2[w][g][q][e] = A[g, v=16*(e>>2)+4q+(e&3), w]  (0 if v>=25 or w>=25)
    for (int i = tid; i < 32 * 96; i += 4096) {
        const int w = i / 96, r = i % 96;
        const int g = r >> 5, q = (r >> 3) & 3, e = r & 7;
        const int v = 16 * (e >> 2) + 4 * q + (e & 3);
        const float val = (w < V_ && v < V_) ? A[g * (V_ * V_) + v * V_ + w] : 0.f;
        reinterpret_cast<unsigned short*>(ws + WS_A2)[i] = cvt_bf16(val);
    }
    // bout[c][w] = sum_k b[k*64+c] * sum_v A[k,v,w]
    for (int i = tid; i < 64 * 32; i += 4096) {
        const int c = i >> 5, w = i & 31;
        float s = 0.f;
        if (w < V_) {
            for (int k = 0; k < 3; ++k) {
                float sa = 0.f;
                for (int v = 0; v < V_; ++v) sa += A[k * (V_ * V_) + v * V_ + w];
                s += bias[k * COUT + c] * sa;
            }
        }
        reinterpret_cast<float*>(ws + WS_B)[i] = s;
    }
}

// ---------------- main: 1 wave = 1 (n,t), no LDS, no barriers ----------------
__global__ __launch_bounds__(256, 3) void gcn_main(
    const float* __restrict__ x, const unsigned char* __restrict__ ws,
    float* __restrict__ out)
{
    const int tid = threadIdx.x;
    const int wv  = tid >> 6, l = tid & 63, lr = l & 15, q = l >> 4;
    const int gid = blockIdx.x * 4 + wv;          // 0..9599
    const int n   = gid / T_;
    const int t   = gid % T_;

    // ---- x loads -> stage1 A-frags  (A[m=lr][k=ci]; v-row = 16h+lr, clamped)
    const float* xb = x + (size_t)n * (CIN * T_ * V_) + t * V_;
    const int v0 = lr;
    const int v1 = (lr + 16 > 24) ? 24 : lr + 16;   // pad rows killed by Ahat2 zeros
    float xf[2][2][8];
    #pragma unroll
    for (int h = 0; h < 2; ++h) {
        const int vv = h ? v1 : v0;
        #pragma unroll
        for (int ks = 0; ks < 2; ++ks)
            #pragma unroll
            for (int e = 0; e < 8; ++e)
                xf[h][ks][e] = xb[(size_t)(ks * 32 + q * 8 + e) * (T_ * V_) + vv];
    }
    bf16x8 afr[2][2];
    #pragma unroll
    for (int h = 0; h < 2; ++h)
        #pragma unroll
        for (int ks = 0; ks < 2; ++ks)
            #pragma unroll
            for (int e = 0; e < 8; ++e)
                afr[h][ks][e] = (short)cvt_bf16(xf[h][ks][e]);

    // ---- out accumulators, bias-folded init from bout
    f32x4 acc2[2][4];
    #pragma unroll
    for (int mt = 0; mt < 2; ++mt)
        #pragma unroll
        for (int cn = 0; cn < 4; ++cn)
            acc2[mt][cn] = *reinterpret_cast<const f32x4*>(
                ws + WS_B + (((cn * 16 + lr) * 32) + mt * 16 + q * 4) * 4);

    // ---- fused per-g: stage1 (16 MFMA) -> in-register handoff -> stage2 (8 MFMA)
    #pragma unroll
    for (int g = 0; g < 3; ++g) {
        bf16x8 wfr[2][4];
        #pragma unroll
        for (int ks = 0; ks < 2; ++ks)
            #pragma unroll
            for (int j = 0; j < 4; ++j)
                wfr[ks][j] = *reinterpret_cast<const bf16x8*>(
                    ws + WS_W + (((g * 4 + j) * 16 + lr) * 64 + ks * 32 + q * 8) * 2);
        bf16x8 a2f[2];
        #pragma unroll
        for (int mt = 0; mt < 2; ++mt)
            a2f[mt] = *reinterpret_cast<const bf16x8*>(
                ws + WS_A2 + (((mt * 16 + lr) * 96) + g * 32 + q * 8) * 2);

        f32x4 acc[4][2];
        #pragma unroll
        for (int j = 0; j < 4; ++j)
            #pragma unroll
            for (int h = 0; h < 2; ++h)
                acc[j][h] = (f32x4){0.f, 0.f, 0.f, 0.f};
        #pragma unroll
        for (int ks = 0; ks < 2; ++ks)
            #pragma unroll
            for (int j = 0; j < 4; ++j)
                #pragma unroll
                for (int h = 0; h < 2; ++h)
                    acc[j][h] = __builtin_amdgcn_mfma_f32_16x16x32_bf16(
                        afr[h][ks], wfr[ks][j], acc[j][h], 0, 0, 0);

        // handoff: B[k=8q+e][c] = bf16(acc[cn][e>>2][e&3])  (khat = 32g+16(e>>2)+4q+(e&3))
        #pragma unroll
        for (int cn = 0; cn < 4; ++cn) {
            bf16x8 bfr;
            #pragma unroll
            for (int e = 0; e < 4; ++e) {
                bfr[e]     = (short)cvt_bf16(acc[cn][0][e]);
                bfr[4 + e] = (short)cvt_bf16(acc[cn][1][e]);
            }
            #pragma unroll
            for (int mt = 0; mt < 2; ++mt)
                acc2[mt][cn] = __builtin_amdgcn_mfma_f32_16x16x32_bf16(
                    a2f[mt], bfr, acc2[mt][cn], 0, 0, 0);
        }
    }

    // ---- store out[n][c][t][w]: lane holds w = 16mt+4q+r, c = 16cn+lr
    #pragma unroll
    for (int mt = 0; mt < 2; ++mt) {
        const int w0 = mt * 16 + q * 4;
        #pragma unroll
        for (int cn = 0; cn < 4; ++cn) {
            const int c = cn * 16 + lr;
            float* op = out + ((size_t)(n * COUT + c) * T_ + t) * V_ + w0;
            #pragma unroll
            for (int r = 0; r < 4; ++r)
                if (w0 + r < V_) op[r] = acc2[mt][cn][r];
        }
    }
}

extern "C" void kernel_launch(void* const* d_in, const int* in_sizes, int n_in,
                              void* d_out, int out_size, void* d_ws, size_t ws_size,
                              hipStream_t stream) {
    const float* x    = (const float*)d_in[0];
    const float* W    = (const float*)d_in[1];
    const float* bias = (const float*)d_in[2];
    const float* A    = (const float*)d_in[3];
    float* out = (float*)d_out;
    unsigned char* ws = (unsigned char*)d_ws;   // needs WS_BYTES = 38912

    hipLaunchKernelGGL(gcn_prep, dim3(16), dim3(256), 0, stream, W, bias, A, ws);
    hipLaunchKernelGGL(gcn_main, dim3(2400), dim3(256), 0, stream, x, ws, out);
}

// Round 8
// 59.509 us; speedup vs baseline: 1.1783x; 1.1783x over previous
//
#include <hip/hip_runtime.h>
#include <hip/hip_bf16.h>

// ST-GCN spatial graph conv — fused two-stage MFMA, global_load_lds x-staging.
//
//   prepass (d_ws): Wbf[192 kc][64 ci] bf16 | As[32 w][104 khat] bf16 (khat=k*32+v,
//                   zeros at v>=25 / khat>=96 / w>=25) | bout[64 c][32 w] f32
//                   (= sum_k b[kc]*sum_v A[k,v,w]; bias folded out of F).
//   main: block = (n, 4 t's), 512 thr / 8 waves.
//     x slice [64 ci][100 (t,v)] f32 -> LDS LINEAR image via 25x global_load_lds
//     dwordx4 (fire-and-forget DMA; 25.6KB in flight, no VGPR cost).
//     stage1: A-frags via ds_read_b32 from Xs (<=4-way conflict), W-frags in
//     registers from ws -> 48 MFMA/wave-pair. F -> Fs LDS (XOR swizzle).
//     stage2: out^T[w][c] = As[w][khat] @ F[khat][c], bout init, 12 MFMA.

#define CIN   64
#define T_    300
#define V_    25
#define OC    192
#define COUT  64
#define TB    4
#define NBLK  (32 * (T_ / TB))   // 2400

#define WS_W    0        // 24576 B : bf16 W[kc][ci]
#define WS_AS   24576    // 6656  B : bf16 As[32][104]
#define WS_B    31232    // 8192  B : f32 bout[64][32]
#define WS_BYTES 39424

#define XS_OFF  0        // 25600 B : f32 Xs[64 ci][100 p]  (linear, gll dest)
#define FS_OFF  25600    // 49152 B : bf16 Fs[192 kc][128 tv], chunk ^= (kc&15)
#define SMEM_BYTES (25600 + 49152)

typedef short  bf16x8 __attribute__((ext_vector_type(8)));
typedef float  f32x4  __attribute__((ext_vector_type(4)));
typedef unsigned int u32x2 __attribute__((ext_vector_type(2)));

__device__ __forceinline__ unsigned short cvt_bf16(float f) {
    union { __hip_bfloat16 h; unsigned short u; } cv;
    cv.h = __float2bfloat16(f);
    return cv.u;
}

#define GLL16(g, s) __builtin_amdgcn_global_load_lds( \
    (const __attribute__((address_space(1))) void*)(g), \
    (__attribute__((address_space(3))) void*)(s), 16, 0, 0)

// ---------------- prepass ----------------
__global__ void gcn_prep(const float* __restrict__ W, const float* __restrict__ bias,
                         const float* __restrict__ A, unsigned char* __restrict__ ws)
{
    const int tid = blockIdx.x * 256 + threadIdx.x;   // 4096 threads
    for (int i = tid; i < OC * CIN; i += 4096)
        reinterpret_cast<unsigned short*>(ws + WS_W)[i] = cvt_bf16(W[i]);
    for (int i = tid; i < 32 * 104; i += 4096) {
        const int wq = i / 104, kh = i % 104;
        const int k = kh >> 5, v = kh & 31;
        const float val = (kh < 96 && wq < V_ && v < V_) ? A[k * 625 + v * 25 + wq] : 0.f;
        reinterpret_cast<unsigned short*>(ws + WS_AS)[i] = cvt_bf16(val);
    }
    for (int i = tid; i < 64 * 32; i += 4096) {
        const int c = i >> 5, w = i & 31;
        float s = 0.f;
        if (w < V_) {
            for (int k = 0; k < 3; ++k) {
                float sa = 0.f;
                for (int v = 0; v < V_; ++v) sa += A[k * (V_ * V_) + v * V_ + w];
                s += bias[k * COUT + c] * sa;
            }
        }
        reinterpret_cast<float*>(ws + WS_B)[i] = s;
    }
}

// ---------------- main ----------------
__global__ __launch_bounds__(512, 4) void gcn_main(
    const float* __restrict__ x, const unsigned char* __restrict__ ws,
    float* __restrict__ out)
{
    __shared__ __align__(16) unsigned char smem[SMEM_BYTES];

    const int tid = threadIdx.x;
    const int bx  = blockIdx.x;
    const int n   = bx / (T_ / TB);
    const int t0  = (bx % (T_ / TB)) * TB;

    const int wv = tid >> 6, l = tid & 63, lr = l & 15, lq = l >> 4;

    // ---- x slice -> LDS linear image, fire-and-forget DMA (25 x 1KB chunks)
    //      Xs float index = ci*100 + p, p = (t-t0)*25 + v. chunk c: floats4 [c*64, c*64+64)
    {
        const float* xsl = x + (size_t)n * (CIN * T_ * V_) + t0 * V_;
        for (int c = wv; c < 25; c += 8) {
            const int f  = c * 64 + l;          // float4 slot 0..1599
            const int ci = f / 25, j = f % 25;
            GLL16(xsl + (size_t)ci * (T_ * V_) + j * 4, smem + XS_OFF + c * 1024);
        }
    }

    // ---- per-block W-frags from ws (L2-hot), in flight during staging
    const int n0 = (wv & 1) * 6;
    bf16x8 wfr[2][6];
    #pragma unroll
    for (int ks = 0; ks < 2; ++ks)
        #pragma unroll
        for (int j = 0; j < 6; ++j) {
            const int o = (n0 + j) * 16 + lr;
            wfr[ks][j] = *reinterpret_cast<const bf16x8*>(
                ws + WS_W + (o * CIN + ks * 32 + lq * 8) * 2);
        }

    __syncthreads();   // drains gll queue (vmcnt 0) + block barrier

    // ---- stage 1: wave pair-task: M-tiles {m0, m0+4}, N-tiles n0..n0+5
    const int m0 = wv >> 1;
    f32x4 acc[2][6];
    #pragma unroll
    for (int h = 0; h < 2; ++h)
        #pragma unroll
        for (int j = 0; j < 6; ++j) acc[h][j] = (f32x4){0.f, 0.f, 0.f, 0.f};

    #pragma unroll
    for (int h = 0; h < 2; ++h) {
        const int m  = m0 + h * 4;
        const int tt = m >> 1;
        const int v  = (m & 1) * 16 + lr;
        const int vc = v > 24 ? 24 : v;          // pad rows killed by As zeros
        const int p  = tt * 25 + vc;
        #pragma unroll
        for (int ks = 0; ks < 2; ++ks) {
            bf16x8 afr;
            #pragma unroll
            for (int e = 0; e < 8; ++e) {
                const int ci = ks * 32 + lq * 8 + e;
                const float xv = *reinterpret_cast<const float*>(
                    smem + XS_OFF + (ci * 100 + p) * 4);
                afr[e] = (short)cvt_bf16(xv);
            }
            #pragma unroll
            for (int j = 0; j < 6; ++j)
                acc[h][j] = __builtin_amdgcn_mfma_f32_16x16x32_bf16(
                    afr, wfr[ks][j], acc[h][j], 0, 0, 0);
        }
    }

    // ---- write F to Fs[kc][tv], chunk ^= (kc&15)
    #pragma unroll
    for (int h = 0; h < 2; ++h) {
        const int tvb = (m0 + h * 4) * 16 + lq * 4;
        #pragma unroll
        for (int j = 0; j < 6; ++j) {
            const int kc = (n0 + j) * 16 + lr;
            u32x2 pk;
            pk[0] = (unsigned)cvt_bf16(acc[h][j][0]) | ((unsigned)cvt_bf16(acc[h][j][1]) << 16);
            pk[1] = (unsigned)cvt_bf16(acc[h][j][2]) | ((unsigned)cvt_bf16(acc[h][j][3]) << 16);
            *reinterpret_cast<u32x2*>(smem + FS_OFF + kc * 256 +
                ((((tvb >> 3) ^ (kc & 15)) << 4)) + (tvb & 7) * 2) = pk;
        }
    }

    // ---- stage-2 constants from ws: issue before barrier (latency hidden)
    const int mt = wv >> 2, nc = wv & 3;
    const int c  = nc * 16 + lr;
    const int w0 = mt * 16 + lq * 4;
    bf16x8 afr2[3];
    #pragma unroll
    for (int ks = 0; ks < 3; ++ks)
        afr2[ks] = *reinterpret_cast<const bf16x8*>(
            ws + WS_AS + ((mt * 16 + lr) * 104 + ks * 32 + lq * 8) * 2);
    const f32x4 binit = *reinterpret_cast<const f32x4*>(
        ws + WS_B + (c * 32 + w0) * 4);

    __syncthreads();

    // ---- stage 2: out^T[w][c] = As[w][khat] @ F[khat][c], loop t
    #pragma unroll
    for (int t = 0; t < TB; ++t) {
        f32x4 a2 = binit;
        #pragma unroll
        for (int ks = 0; ks < 3; ++ks) {
            const int kc = ks * 64 + c;
            const bf16x8 bfr = *reinterpret_cast<bf16x8*>(
                smem + FS_OFF + kc * 256 + ((((t * 4 + lq) ^ (kc & 15)) << 4)));
            a2 = __builtin_amdgcn_mfma_f32_16x16x32_bf16(afr2[ks], bfr, a2, 0, 0, 0);
        }
        float* op = out + ((size_t)(n * COUT + c) * T_ + (t0 + t)) * V_;
        if (w0 + 3 < V_) {
            #pragma unroll
            for (int e = 0; e < 4; ++e) op[w0 + e] = a2[e];
        } else {
            #pragma unroll
            for (int e = 0; e < 4; ++e) if (w0 + e < V_) op[w0 + e] = a2[e];
        }
    }
}

extern "C" void kernel_launch(void* const* d_in, const int* in_sizes, int n_in,
                              void* d_out, int out_size, void* d_ws, size_t ws_size,
                              hipStream_t stream) {
    const float* x    = (const float*)d_in[0];
    const float* W    = (const float*)d_in[1];
    const float* bias = (const float*)d_in[2];
    const float* A    = (const float*)d_in[3];
    float* out = (float*)d_out;
    unsigned char* ws = (unsigned char*)d_ws;   // needs WS_BYTES = 39424

    hipLaunchKernelGGL(gcn_prep, dim3(16), dim3(256), 0, stream, W, bias, A, ws);
    hipLaunchKernelGGL(gcn_main, dim3(NBLK), dim3(512), 0, stream, x, ws, out);
}

// Round 9
// 56.084 us; speedup vs baseline: 1.2503x; 1.0611x over previous
//
#include <hip/hip_runtime.h>
#include <hip/hip_bf16.h>

// ST-GCN spatial graph conv — fused two-stage MFMA + COALESCED STORE PATH.
//
//   prepass (d_ws): Wbf[192 kc][64 ci] bf16 | As[32 w][104 khat] bf16 (khat=k*32+v,
//                   zeros at v>=25 / khat>=96 / w>=25) | bout[64 c][32 w] f32
//                   (= sum_k b[kc]*sum_v A[k,v,w]; bias folded out of F).
//   main: block = (n, 4 t's), 512 thr / 8 waves.
//     x slice -> LDS linear via 25x global_load_lds dwordx4 (fire-and-forget DMA).
//     stage1: A-frags via ds_read from Xs; W-frags in registers from ws. 24 MFMA/wave.
//     F -> Fs LDS (XOR swizzle). stage2: out^T[w][c] = As @ F, bout init, 12 MFMA.
//     NEW: stage-2 accs -> Os[64c][100p] f32 LDS tile (aliases dead Xs), then
//     coalesced sweep: 25x global_store_dwordx4 per block (was 128 instrs x 64
//     scattered lines = 8192 write transactions/block -> now ~425).

#define CIN   64
#define T_    300
#define V_    25
#define OC    192
#define COUT  64
#define TB    4
#define NBLK  (32 * (T_ / TB))   // 2400

#define WS_W    0        // 24576 B : bf16 W[kc][ci]
#define WS_AS   24576    // 6656  B : bf16 As[32][104]
#define WS_B    31232    // 8192  B : f32 bout[64][32]
#define WS_BYTES 39424

#define XS_OFF  0        // 25600 B : f32 Xs[64 ci][100 p]  (linear, gll dest)
#define OS_OFF  0        // 25600 B : f32 Os[64 c][100 p]   (aliases Xs, dead after stage1)
#define FS_OFF  25600    // 49152 B : bf16 Fs[192 kc][128 tv], chunk ^= (kc&15)
#define SMEM_BYTES (25600 + 49152)

typedef short  bf16x8 __attribute__((ext_vector_type(8)));
typedef float  f32x4  __attribute__((ext_vector_type(4)));
typedef unsigned int u32x2 __attribute__((ext_vector_type(2)));

__device__ __forceinline__ unsigned short cvt_bf16(float f) {
    union { __hip_bfloat16 h; unsigned short u; } cv;
    cv.h = __float2bfloat16(f);
    return cv.u;
}

#define GLL16(g, s) __builtin_amdgcn_global_load_lds( \
    (const __attribute__((address_space(1))) void*)(g), \
    (__attribute__((address_space(3))) void*)(s), 16, 0, 0)

// ---------------- prepass ----------------
__global__ void gcn_prep(const float* __restrict__ W, const float* __restrict__ bias,
                         const float* __restrict__ A, unsigned char* __restrict__ ws)
{
    const int tid = blockIdx.x * 256 + threadIdx.x;   // 4096 threads
    for (int i = tid; i < OC * CIN; i += 4096)
        reinterpret_cast<unsigned short*>(ws + WS_W)[i] = cvt_bf16(W[i]);
    for (int i = tid; i < 32 * 104; i += 4096) {
        const int wq = i / 104, kh = i % 104;
        const int k = kh >> 5, v = kh & 31;
        const float val = (kh < 96 && wq < V_ && v < V_) ? A[k * 625 + v * 25 + wq] : 0.f;
        reinterpret_cast<unsigned short*>(ws + WS_AS)[i] = cvt_bf16(val);
    }
    for (int i = tid; i < 64 * 32; i += 4096) {
        const int c = i >> 5, w = i & 31;
        float s = 0.f;
        if (w < V_) {
            for (int k = 0; k < 3; ++k) {
                float sa = 0.f;
                for (int v = 0; v < V_; ++v) sa += A[k * (V_ * V_) + v * V_ + w];
                s += bias[k * COUT + c] * sa;
            }
        }
        reinterpret_cast<float*>(ws + WS_B)[i] = s;
    }
}

// ---------------- main ----------------
__global__ __launch_bounds__(512, 4) void gcn_main(
    const float* __restrict__ x, const unsigned char* __restrict__ ws,
    float* __restrict__ out)
{
    __shared__ __align__(16) unsigned char smem[SMEM_BYTES];

    const int tid = threadIdx.x;
    const int bx  = blockIdx.x;
    const int n   = bx / (T_ / TB);
    const int t0  = (bx % (T_ / TB)) * TB;

    const int wv = tid >> 6, l = tid & 63, lr = l & 15, lq = l >> 4;

    // ---- x slice -> LDS linear image, fire-and-forget DMA (25 x 1KB chunks)
    {
        const float* xsl = x + (size_t)n * (CIN * T_ * V_) + t0 * V_;
        for (int cch = wv; cch < 25; cch += 8) {
            const int f  = cch * 64 + l;        // float4 slot 0..1599
            const int ci = f / 25, j = f % 25;
            GLL16(xsl + (size_t)ci * (T_ * V_) + j * 4, smem + XS_OFF + cch * 1024);
        }
    }

    // ---- per-block W-frags from ws (L2-hot), in flight during staging
    const int n0 = (wv & 1) * 6;
    bf16x8 wfr[2][6];
    #pragma unroll
    for (int ks = 0; ks < 2; ++ks)
        #pragma unroll
        for (int j = 0; j < 6; ++j) {
            const int o = (n0 + j) * 16 + lr;
            wfr[ks][j] = *reinterpret_cast<const bf16x8*>(
                ws + WS_W + (o * CIN + ks * 32 + lq * 8) * 2);
        }

    __syncthreads();   // drains gll queue + block barrier

    // ---- stage 1: wave: M-tiles {m0, m0+4}, N-tiles n0..n0+5
    const int m0 = wv >> 1;
    f32x4 acc[2][6];
    #pragma unroll
    for (int h = 0; h < 2; ++h)
        #pragma unroll
        for (int j = 0; j < 6; ++j) acc[h][j] = (f32x4){0.f, 0.f, 0.f, 0.f};

    #pragma unroll
    for (int h = 0; h < 2; ++h) {
        const int m  = m0 + h * 4;
        const int tt = m >> 1;
        const int v  = (m & 1) * 16 + lr;
        const int vc = v > 24 ? 24 : v;          // pad rows killed by As zeros
        const int p  = tt * 25 + vc;
        #pragma unroll
        for (int ks = 0; ks < 2; ++ks) {
            bf16x8 afr;
            #pragma unroll
            for (int e = 0; e < 8; ++e) {
                const int ci = ks * 32 + lq * 8 + e;
                const float xv = *reinterpret_cast<const float*>(
                    smem + XS_OFF + (ci * 100 + p) * 4);
                afr[e] = (short)cvt_bf16(xv);
            }
            #pragma unroll
            for (int j = 0; j < 6; ++j)
                acc[h][j] = __builtin_amdgcn_mfma_f32_16x16x32_bf16(
                    afr, wfr[ks][j], acc[h][j], 0, 0, 0);
        }
    }

    // ---- write F to Fs[kc][tv], chunk ^= (kc&15)
    #pragma unroll
    for (int h = 0; h < 2; ++h) {
        const int tvb = (m0 + h * 4) * 16 + lq * 4;
        #pragma unroll
        for (int j = 0; j < 6; ++j) {
            const int kc = (n0 + j) * 16 + lr;
            u32x2 pk;
            pk[0] = (unsigned)cvt_bf16(acc[h][j][0]) | ((unsigned)cvt_bf16(acc[h][j][1]) << 16);
            pk[1] = (unsigned)cvt_bf16(acc[h][j][2]) | ((unsigned)cvt_bf16(acc[h][j][3]) << 16);
            *reinterpret_cast<u32x2*>(smem + FS_OFF + kc * 256 +
                ((((tvb >> 3) ^ (kc & 15)) << 4)) + (tvb & 7) * 2) = pk;
        }
    }

    // ---- stage-2 constants from ws: issue before barrier (latency hidden)
    const int mt = wv >> 2, nc = wv & 3;
    const int c  = nc * 16 + lr;
    const int w0 = mt * 16 + lq * 4;
    bf16x8 afr2[3];
    #pragma unroll
    for (int ks = 0; ks < 3; ++ks)
        afr2[ks] = *reinterpret_cast<const bf16x8*>(
            ws + WS_AS + ((mt * 16 + lr) * 104 + ks * 32 + lq * 8) * 2);
    const f32x4 binit = *reinterpret_cast<const f32x4*>(
        ws + WS_B + (c * 32 + w0) * 4);

    __syncthreads();   // Fs ready; also: all Xs reads done -> Os may alias

    // ---- stage 2: out^T[w][c] = As[w][khat] @ F[khat][c] -> Os LDS tile
    float* osw = reinterpret_cast<float*>(smem + OS_OFF);
    #pragma unroll
    for (int t = 0; t < TB; ++t) {
        f32x4 a2 = binit;
        #pragma unroll
        for (int ks = 0; ks < 3; ++ks) {
            const int kc = ks * 64 + c;
            const bf16x8 bfr = *reinterpret_cast<bf16x8*>(
                smem + FS_OFF + kc * 256 + ((((t * 4 + lq) ^ (kc & 15)) << 4)));
            a2 = __builtin_amdgcn_mfma_f32_16x16x32_bf16(afr2[ks], bfr, a2, 0, 0, 0);
        }
        #pragma unroll
        for (int e = 0; e < 4; ++e)
            if (w0 + e < V_)
                osw[c * 100 + t * 25 + w0 + e] = a2[e];
    }

    __syncthreads();   // Os complete

    // ---- coalesced store sweep: 1600 float4s, 16B-aligned both sides
    {
        const float* osr = reinterpret_cast<const float*>(smem + OS_OFF);
        float* ob = out + (size_t)n * (COUT * T_ * V_) + t0 * V_;
        for (int i = tid; i < 1600; i += 512) {
            const int cc = i / 25, j = i % 25;
            const f32x4 vv = *reinterpret_cast<const f32x4*>(osr + cc * 100 + j * 4);
            *reinterpret_cast<f32x4*>(ob + (size_t)cc * (T_ * V_) + j * 4) = vv;
        }
    }
}

extern "C" void kernel_launch(void* const* d_in, const int* in_sizes, int n_in,
                              void* d_out, int out_size, void* d_ws, size_t ws_size,
                              hipStream_t stream) {
    const float* x    = (const float*)d_in[0];
    const float* W    = (const float*)d_in[1];
    const float* bias = (const float*)d_in[2];
    const float* A    = (const float*)d_in[3];
    float* out = (float*)d_out;
    unsigned char* ws = (unsigned char*)d_ws;   // needs WS_BYTES = 39424

    hipLaunchKernelGGL(gcn_prep, dim3(16), dim3(256), 0, stream, W, bias, A, ws);
    hipLaunchKernelGGL(gcn_main, dim3(NBLK), dim3(512), 0, stream, x, ws, out);
}

// Round 10
// 46.369 us; speedup vs baseline: 1.5122x; 1.2095x over previous
//
#include <hip/hip_runtime.h>
#include <hip/hip_bf16.h>

// ST-GCN spatial graph conv — SWAPPED contraction order, single-wave, zero-LDS,
// zero-barrier, fully in-register two-stage MFMA.
//
//   stage A (per n,t):  y[ci][32k+w] = sum_v x[n,ci,t,v] * A[k,v,w]
//       K-axis = v  -> per-lane x frag = 8 CONSECUTIVE floats (2 aligned f32x4).
//       Alignment: base t*25 has dword phase d=t&3; load from Q=t*25-d and use
//       the d-shifted Ahat image AhatT4[d][vp][kw] (vp=v+d, zeros outside).
//       (t=299 -> d=3 -> max idx 7499: in bounds; t=0 -> d=0: no underflow.)
//   stage B:  out[c][w] = sum_{k,ci} W[64k+c][ci] * y[ci][32k+w]   (K=192, 6 steps)
//       W2img pre-permutes W's K-axis: slot(kap;lq,e) -> ci = 32(kap&1)+16(e>>2)+4lq+(e&3),
//       so each lane's B-frag == its OWN stage-A accumulator values (bf16-cvt) —
//       no LDS, no shuffles (R7 handoff trick, now with vectorizable x loads).
//   bias folded into bout[c][w] = sum_k b[64k+c]*sum_v A[k,v,w] (out-init image).
//
// 9600 waves (one per (n,t)), 2400 blocks x 256 thr. 72 MFMA + ~46 vec loads/wave.

#define CIN   64
#define T_    300
#define V_    25
#define COUT  64

#define WS_W2 0        // 24576 B : bf16 W2img[(ct*6+kap)*64 + lane][8]
#define WS_AH 24576    // 24576 B : bf16 AhatT4[d(4)][kw(96)][vp(32)]
#define WS_BO 49152    // 8192  B : f32  boutT[w(32)][c(64)]
#define WS_BYTES 57344

typedef short  bf16x8 __attribute__((ext_vector_type(8)));
typedef float  f32x4  __attribute__((ext_vector_type(4)));

__device__ __forceinline__ unsigned short cvt_bf16(float f) {
    union { __hip_bfloat16 h; unsigned short u; } cv;
    cv.h = __float2bfloat16(f);
    return cv.u;
}
__device__ __forceinline__ unsigned pk2(float a, float b) {
    return (unsigned)cvt_bf16(a) | ((unsigned)cvt_bf16(b) << 16);
}
union fragu { bf16x8 v; unsigned u[4]; };

// ---------------- prepass: bake W2img / AhatT4 / boutT ----------------
__global__ void gcn_prep(const float* __restrict__ W, const float* __restrict__ bias,
                         const float* __restrict__ A, unsigned char* __restrict__ ws)
{
    const int tid = blockIdx.x * 256 + threadIdx.x;   // 4096 threads
    // W2img[((ct*6+kap)*64 + lane)*8 + e] = W[(kap>>1)*64 + 16ct + lr][32(kap&1)+16(e>>2)+4lq+(e&3)]
    for (int i = tid; i < 4 * 6 * 64 * 8; i += 4096) {
        const int e = i & 7, lane = (i >> 3) & 63, ck = i >> 9;   // ck = ct*6+kap
        const int kap = ck % 6, ct = ck / 6;
        const int lr = lane & 15, lq = lane >> 4;
        const int row = (kap >> 1) * COUT + ct * 16 + lr;
        const int col = 32 * (kap & 1) + 16 * (e >> 2) + 4 * lq + (e & 3);
        reinterpret_cast<unsigned short*>(ws + WS_W2)[i] = cvt_bf16(W[row * CIN + col]);
    }
    // AhatT4[d][kw][vp] = A[kw>>5][vp-d][kw&31]  (0 outside v in [0,25), w<25)
    for (int i = tid; i < 4 * 96 * 32; i += 4096) {
        const int vp = i & 31, kw = (i >> 5) % 96, dd = (i >> 5) / 96;
        const int k = kw >> 5, w = kw & 31, v = vp - dd;
        const float val = (v >= 0 && v < V_ && w < V_) ? A[(k * V_ + v) * V_ + w] : 0.f;
        reinterpret_cast<unsigned short*>(ws + WS_AH)[i] = cvt_bf16(val);
    }
    // boutT[w][c] = sum_k b[64k+c] * sum_v A[k,v,w]
    for (int i = tid; i < 32 * 64; i += 4096) {
        const int w = i >> 6, c = i & 63;
        float s = 0.f;
        if (w < V_) {
            for (int k = 0; k < 3; ++k) {
                float sa = 0.f;
                for (int v = 0; v < V_; ++v) sa += A[(k * V_ + v) * V_ + w];
                s += bias[k * COUT + c] * sa;
            }
        }
        reinterpret_cast<float*>(ws + WS_BO)[i] = s;
    }
}

// ---------------- main: 1 wave = 1 (n,t) ----------------
__global__ __launch_bounds__(256, 2) void gcn_main(
    const float* __restrict__ x, const unsigned char* __restrict__ ws,
    float* __restrict__ out)
{
    const int tid = threadIdx.x;
    const int l = tid & 63, lr = l & 15, lq = l >> 4;
    const int gid = blockIdx.x * 4 + (tid >> 6);      // 0..9599
    const int n = gid / T_, t = gid % T_;
    const int d = t & 3;                              // wave-uniform dword phase
    const int qoff = t * V_ - d;                      // 16B-aligned float offset

    // ---- x loads: per mi (ci-tile), two aligned f32x4 covering vp = 8lq..8lq+7
    const float* xrow = x + (size_t)(n * CIN + lr) * (T_ * V_) + qoff + 8 * lq;
    f32x4 xa[4], xg[4];
    #pragma unroll
    for (int mi = 0; mi < 4; ++mi) {
        const float* p = xrow + (size_t)mi * 16 * (T_ * V_);
        xa[mi] = *reinterpret_cast<const f32x4*>(p);
        // lq==3: second chunk (vp=28..31) multiplies all-zero Ahat rows -> load
        // duplicate of first chunk instead (keeps last-row access <= idx 7499).
        xg[mi] = *reinterpret_cast<const f32x4*>(p + (lq < 3 ? 4 : 0));
    }

    // ---- Ahat frags for this d: B[vp-slot=8lq+e][kw-col=16ni+lr]
    const unsigned char* ahb = ws + WS_AH + d * (96 * 32 * 2);
    bf16x8 ah[6];
    #pragma unroll
    for (int ni = 0; ni < 6; ++ni)
        ah[ni] = *reinterpret_cast<const bf16x8*>(ahb + ((16 * ni + lr) * 32 + 8 * lq) * 2);

    // ---- out accumulators, bias-folded init
    f32x4 oacc[4][2];
    #pragma unroll
    for (int ct = 0; ct < 4; ++ct)
        #pragma unroll
        for (int nt = 0; nt < 2; ++nt)
            oacc[ct][nt] = *reinterpret_cast<const f32x4*>(
                ws + WS_BO + ((16 * nt + lr) * 64 + 16 * ct + 4 * lq) * 4);

    // ---- x -> bf16 A-frags
    bf16x8 xf[4];
    #pragma unroll
    for (int mi = 0; mi < 4; ++mi) {
        fragu f;
        f.u[0] = pk2(xa[mi][0], xa[mi][1]);
        f.u[1] = pk2(xa[mi][2], xa[mi][3]);
        f.u[2] = pk2(xg[mi][0], xg[mi][1]);
        f.u[3] = pk2(xg[mi][2], xg[mi][3]);
        xf[mi] = f.v;
    }

    // ---- fused stages, per k: stage A (8 MFMA) -> in-register handoff -> stage B (16 MFMA)
    #pragma unroll
    for (int k = 0; k < 3; ++k) {
        bf16x8 w2f[2][4];
        #pragma unroll
        for (int kl = 0; kl < 2; ++kl)
            #pragma unroll
            for (int ct = 0; ct < 4; ++ct)
                w2f[kl][ct] = *reinterpret_cast<const bf16x8*>(
                    ws + WS_W2 + ((ct * 6 + 2 * k + kl) * 64 + l) * 16);

        f32x4 y[4][2];
        #pragma unroll
        for (int mi = 0; mi < 4; ++mi)
            #pragma unroll
            for (int j = 0; j < 2; ++j)
                y[mi][j] = (f32x4){0.f, 0.f, 0.f, 0.f};
        #pragma unroll
        for (int j = 0; j < 2; ++j)
            #pragma unroll
            for (int mi = 0; mi < 4; ++mi)
                y[mi][j] = __builtin_amdgcn_mfma_f32_16x16x32_bf16(
                    xf[mi], ah[2 * k + j], y[mi][j], 0, 0, 0);

        // handoff: B-frag[e] = bf16(y[2kl + (e>>2)][nt][e&3])  — all lane-local
        #pragma unroll
        for (int kl = 0; kl < 2; ++kl)
            #pragma unroll
            for (int nt = 0; nt < 2; ++nt) {
                fragu b;
                b.u[0] = pk2(y[2 * kl][nt][0],     y[2 * kl][nt][1]);
                b.u[1] = pk2(y[2 * kl][nt][2],     y[2 * kl][nt][3]);
                b.u[2] = pk2(y[2 * kl + 1][nt][0], y[2 * kl + 1][nt][1]);
                b.u[3] = pk2(y[2 * kl + 1][nt][2], y[2 * kl + 1][nt][3]);
                #pragma unroll
                for (int ct = 0; ct < 4; ++ct)
                    oacc[ct][nt] = __builtin_amdgcn_mfma_f32_16x16x32_bf16(
                        w2f[kl][ct], b.v, oacc[ct][nt], 0, 0, 0);
            }
    }

    // ---- store: lane holds out[c = 16ct+4lq+r][w = 16nt+lr]
    float* ob = out + ((size_t)(n * COUT) * T_ + t) * V_;
    #pragma unroll
    for (int ct = 0; ct < 4; ++ct) {
        #pragma unroll
        for (int r = 0; r < 4; ++r) {
            const int c = 16 * ct + 4 * lq + r;
            float* op = ob + (size_t)c * (T_ * V_);
            op[lr] = oacc[ct][0][r];
            if (lr < 9) op[16 + lr] = oacc[ct][1][r];
        }
    }
}

extern "C" void kernel_launch(void* const* d_in, const int* in_sizes, int n_in,
                              void* d_out, int out_size, void* d_ws, size_t ws_size,
                              hipStream_t stream) {
    const float* x    = (const float*)d_in[0];
    const float* W    = (const float*)d_in[1];
    const float* bias = (const float*)d_in[2];
    const float* A    = (const float*)d_in[3];
    float* out = (float*)d_out;
    unsigned char* ws = (unsigned char*)d_ws;   // needs WS_BYTES = 57344

    hipLaunchKernelGGL(gcn_prep, dim3(16), dim3(256), 0, stream, W, bias, A, ws);
    hipLaunchKernelGGL(gcn_main, dim3(2400), dim3(256), 0, stream, x, ws, out);
}